// Round 1
// baseline (3918.156 us; speedup 1.0000x reference)
//
#include <hip/hip_runtime.h>
#include <math.h>

#define N_NODES 50000
#define D 128
#define MIN_NORM 1e-15f
#define EPS 1e-5f

// h = logmap0(x):  h[:,0]=0 ; h[:,1:] = acosh(max(x0,1+eps)) * y/||y||
__global__ void logmap0_kernel(const float* __restrict__ x, float* __restrict__ h) {
    int row = blockIdx.x;
    int lane = threadIdx.x;              // 64 threads, each owns 2 columns
    const float2* xr = reinterpret_cast<const float2*>(x + (size_t)row * D);
    float2 v = xr[lane];
    float x0 = __shfl(v.x, 0, 64);       // x[row][0]
    float sq = v.y * v.y + (lane == 0 ? 0.0f : v.x * v.x);
    #pragma unroll
    for (int off = 1; off < 64; off <<= 1) sq += __shfl_xor(sq, off, 64);
    float ynorm = fmaxf(sqrtf(sq), MIN_NORM);
    float theta = fmaxf(x0, 1.0f + EPS);
    float scale = acoshf(theta) / ynorm;
    float2 o;
    o.x = (lane == 0) ? 0.0f : v.x * scale;
    o.y = v.y * scale;
    reinterpret_cast<float2*>(h + (size_t)row * D)[lane] = o;
}

// One wave per edge; lane owns 2 columns. hout must be pre-zeroed.
__global__ void spmm_atomic_kernel(const int* __restrict__ rows,
                                   const int* __restrict__ cols,
                                   const float* __restrict__ vals,
                                   const float* __restrict__ hin,
                                   float* __restrict__ hout, int E) {
    int gtid = blockIdx.x * blockDim.x + threadIdx.x;
    int e = gtid >> 6;
    if (e >= E) return;
    int lane = gtid & 63;
    int r = rows[e];
    int c = cols[e];
    float v = vals[e];
    const float2* hi = reinterpret_cast<const float2*>(hin + (size_t)c * D);
    float2 hv = hi[lane];
    float* po = hout + (size_t)r * D + 2 * lane;
    if (lane != 0) unsafeAtomicAdd(po, v * hv.x);   // col 0 is always 0 — skip
    unsafeAtomicAdd(po + 1, v * hv.y);
}

// out = proj(expmap0(h)):  vn=||h[:,1:]|| ; out[:,1:] = sinh(vn)/vn * h[:,1:]
//                          out[:,0] = sqrt(max(1 + sinh(vn)^2, EPS))
__global__ void expmap_proj_kernel(const float* __restrict__ h, float* __restrict__ out) {
    int row = blockIdx.x;
    int lane = threadIdx.x;
    const float2* hr = reinterpret_cast<const float2*>(h + (size_t)row * D);
    float2 v = hr[lane];
    float sq = v.y * v.y + (lane == 0 ? 0.0f : v.x * v.x);
    #pragma unroll
    for (int off = 1; off < 64; off <<= 1) sq += __shfl_xor(sq, off, 64);
    float vn = fmaxf(sqrtf(sq), MIN_NORM);
    float sh = sinhf(vn);
    float scale = sh / vn;
    float first = sqrtf(fmaxf(1.0f + sh * sh, EPS));
    float2 o;
    o.x = (lane == 0) ? first : v.x * scale;
    o.y = v.y * scale;
    reinterpret_cast<float2*>(out + (size_t)row * D)[lane] = o;
}

extern "C" void kernel_launch(void* const* d_in, const int* in_sizes, int n_in,
                              void* d_out, int out_size, void* d_ws, size_t ws_size,
                              hipStream_t stream) {
    const float* x    = (const float*)d_in[0];
    const int*   rows = (const int*)d_in[1];
    const int*   cols = (const int*)d_in[2];
    const float* vals = (const float*)d_in[3];
    float* out = (float*)d_out;
    int E = in_sizes[1];

    float* bufA = (float*)d_ws;   // N*D floats = 25.6 MB scratch
    float* bufB = out;            // reuse output buffer as ping-pong partner
    size_t feat_bytes = (size_t)N_NODES * D * sizeof(float);

    int spmm_threads = 256;
    long long total = (long long)E * 64;
    int spmm_blocks = (int)((total + spmm_threads - 1) / spmm_threads);

    // h0 = logmap0(x) -> A
    logmap0_kernel<<<N_NODES, 64, 0, stream>>>(x, bufA);

    // layer 1: A -> B
    hipMemsetAsync(bufB, 0, feat_bytes, stream);
    spmm_atomic_kernel<<<spmm_blocks, spmm_threads, 0, stream>>>(rows, cols, vals, bufA, bufB, E);
    // layer 2: B -> A
    hipMemsetAsync(bufA, 0, feat_bytes, stream);
    spmm_atomic_kernel<<<spmm_blocks, spmm_threads, 0, stream>>>(rows, cols, vals, bufB, bufA, E);
    // layer 3: A -> B (= out)
    hipMemsetAsync(bufB, 0, feat_bytes, stream);
    spmm_atomic_kernel<<<spmm_blocks, spmm_threads, 0, stream>>>(rows, cols, vals, bufA, bufB, E);

    // out = proj(expmap0(h3)), in place on out (row-local)
    expmap_proj_kernel<<<N_NODES, 64, 0, stream>>>(bufB, out);
}

// Round 2
// 585.273 us; speedup vs baseline: 6.6946x; 6.6946x over previous
//
#include <hip/hip_runtime.h>
#include <math.h>

#define N_NODES 50000
#define D 128
#define MIN_NORM 1e-15f
#define EPS 1e-5f

// ---------------------------------------------------------------------------
// h = logmap0(x):  h[:,0]=0 ; h[:,1:] = acosh(max(x0,1+eps)) * y/||y||
// one wave per row, lane owns 2 columns (float2)
// ---------------------------------------------------------------------------
__global__ void logmap0_kernel(const float* __restrict__ x, float* __restrict__ h) {
    int row = blockIdx.x;
    int lane = threadIdx.x;
    const float2* xr = reinterpret_cast<const float2*>(x + (size_t)row * D);
    float2 v = xr[lane];
    float x0 = __shfl(v.x, 0, 64);
    float sq = v.y * v.y + (lane == 0 ? 0.0f : v.x * v.x);
    #pragma unroll
    for (int off = 1; off < 64; off <<= 1) sq += __shfl_xor(sq, off, 64);
    float ynorm = fmaxf(sqrtf(sq), MIN_NORM);
    float theta = fmaxf(x0, 1.0f + EPS);
    float scale = acoshf(theta) / ynorm;
    float2 o;
    o.x = (lane == 0) ? 0.0f : v.x * scale;
    o.y = v.y * scale;
    reinterpret_cast<float2*>(h + (size_t)row * D)[lane] = o;
}

// ---------------------------------------------------------------------------
// CSR build: histogram -> scan -> scatter
// ---------------------------------------------------------------------------
__global__ void hist_kernel(const int* __restrict__ rows, int* __restrict__ cnt, int E) {
    int e = blockIdx.x * blockDim.x + threadIdx.x;
    if (e < E) atomicAdd(&cnt[rows[e]], 1);
}

// single block, 1024 threads; cursor holds counts on entry, exclusive prefix on exit
__global__ __launch_bounds__(1024) void scan_kernel(int* __restrict__ cursor,
                                                    int* __restrict__ rowptr) {
    __shared__ int wsum[16];
    __shared__ int sbase;
    int tid = threadIdx.x;
    int lane = tid & 63, wid = tid >> 6;
    if (tid == 0) { sbase = 0; rowptr[0] = 0; }
    __syncthreads();
    for (int start = 0; start < N_NODES; start += 1024) {
        int i = start + tid;
        int v = (i < N_NODES) ? cursor[i] : 0;
        int x = v;
        #pragma unroll
        for (int off = 1; off < 64; off <<= 1) {
            int t = __shfl_up(x, off, 64);
            if (lane >= off) x += t;
        }
        if (lane == 63) wsum[wid] = x;
        __syncthreads();
        if (wid == 0) {
            int w = (lane < 16) ? wsum[lane] : 0;
            #pragma unroll
            for (int off = 1; off < 16; off <<= 1) {
                int t = __shfl_up(w, off, 64);
                if (lane >= off) w += t;
            }
            if (lane < 16) wsum[lane] = w;
        }
        __syncthreads();
        int waveoff = (wid == 0) ? 0 : wsum[wid - 1];
        int base = sbase;
        int incl = base + waveoff + x;
        if (i < N_NODES) {
            rowptr[i + 1] = incl;      // inclusive prefix -> rowptr[i+1]
            cursor[i] = incl - v;      // exclusive prefix -> scatter cursor
        }
        __syncthreads();
        if (tid == 1023) sbase = incl; // base + chunk total
        __syncthreads();
    }
}

__global__ void scatter_kernel(const int* __restrict__ rows, const int* __restrict__ cols,
                               const float* __restrict__ vals, int* __restrict__ cursor,
                               int* __restrict__ scol, float* __restrict__ sval, int E) {
    int e = blockIdx.x * blockDim.x + threadIdx.x;
    if (e >= E) return;
    int r = rows[e];
    int pos = atomicAdd(&cursor[r], 1);
    scol[pos] = cols[e];
    sval[pos] = vals[e];
}

// ---------------------------------------------------------------------------
// CSR SpMM: one wave per row, register accumulate, single streamed write.
// FINAL=true fuses out = proj(expmap0(acc)).
// ---------------------------------------------------------------------------
template <bool FINAL>
__global__ __launch_bounds__(256) void spmm_csr_kernel(const int* __restrict__ rowptr,
                                                       const int* __restrict__ scol,
                                                       const float* __restrict__ sval,
                                                       const float* __restrict__ hin,
                                                       float* __restrict__ hout) {
    int wid = threadIdx.x >> 6, lane = threadIdx.x & 63;
    int row = blockIdx.x * 4 + wid;
    if (row >= N_NODES) return;
    int j = rowptr[row], end = rowptr[row + 1];
    float ax = 0.f, ay = 0.f;
    for (; j + 4 <= end; j += 4) {
        int c0 = scol[j], c1 = scol[j + 1], c2 = scol[j + 2], c3 = scol[j + 3];
        float v0 = sval[j], v1 = sval[j + 1], v2 = sval[j + 2], v3 = sval[j + 3];
        float2 h0 = reinterpret_cast<const float2*>(hin + (size_t)c0 * D)[lane];
        float2 h1 = reinterpret_cast<const float2*>(hin + (size_t)c1 * D)[lane];
        float2 h2 = reinterpret_cast<const float2*>(hin + (size_t)c2 * D)[lane];
        float2 h3 = reinterpret_cast<const float2*>(hin + (size_t)c3 * D)[lane];
        ax += v0 * h0.x; ay += v0 * h0.y;
        ax += v1 * h1.x; ay += v1 * h1.y;
        ax += v2 * h2.x; ay += v2 * h2.y;
        ax += v3 * h3.x; ay += v3 * h3.y;
    }
    for (; j < end; ++j) {
        int c = scol[j];
        float v = sval[j];
        float2 hv = reinterpret_cast<const float2*>(hin + (size_t)c * D)[lane];
        ax += v * hv.x; ay += v * hv.y;
    }
    float2 o;
    if (!FINAL) {
        o.x = ax; o.y = ay;
    } else {
        // out = proj(expmap0(acc)); acc col 0 (lane 0, ax) is 0 by construction
        float sq = ay * ay + (lane == 0 ? 0.0f : ax * ax);
        #pragma unroll
        for (int off = 1; off < 64; off <<= 1) sq += __shfl_xor(sq, off, 64);
        float vn = fmaxf(sqrtf(sq), MIN_NORM);
        float sh = sinhf(vn);
        float scale = sh / vn;
        float first = sqrtf(fmaxf(1.0f + sh * sh, EPS));
        o.x = (lane == 0) ? first : ax * scale;
        o.y = ay * scale;
    }
    reinterpret_cast<float2*>(hout + (size_t)row * D)[lane] = o;
}

// ---------------------------------------------------------------------------
extern "C" void kernel_launch(void* const* d_in, const int* in_sizes, int n_in,
                              void* d_out, int out_size, void* d_ws, size_t ws_size,
                              hipStream_t stream) {
    const float* x    = (const float*)d_in[0];
    const int*   rows = (const int*)d_in[1];
    const int*   cols = (const int*)d_in[2];
    const float* vals = (const float*)d_in[3];
    float* out = (float*)d_out;
    int E = in_sizes[1];

    // workspace layout
    float* bufA   = (float*)d_ws;                        // N*D floats (25.6 MB)
    int*   rowptr = (int*)(bufA + (size_t)N_NODES * D);  // N+1
    int*   cursor = rowptr + N_NODES + 1;                // N
    int*   scol   = cursor + N_NODES;                    // E
    float* sval   = (float*)(scol + E);                  // E

    int eb = (E + 255) / 256;
    int sb = (N_NODES + 3) / 4;

    // h0 = logmap0(x) -> bufA
    logmap0_kernel<<<N_NODES, 64, 0, stream>>>(x, bufA);

    // CSR build (per call; cheap int ops)
    hipMemsetAsync(cursor, 0, N_NODES * sizeof(int), stream);
    hist_kernel<<<eb, 256, 0, stream>>>(rows, cursor, E);
    scan_kernel<<<1, 1024, 0, stream>>>(cursor, rowptr);
    scatter_kernel<<<eb, 256, 0, stream>>>(rows, cols, vals, cursor, scol, sval, E);

    // layer 1: bufA -> out
    spmm_csr_kernel<false><<<sb, 256, 0, stream>>>(rowptr, scol, sval, bufA, out);
    // layer 2: out -> bufA
    spmm_csr_kernel<false><<<sb, 256, 0, stream>>>(rowptr, scol, sval, out, bufA);
    // layer 3 + expmap + proj: bufA -> out
    spmm_csr_kernel<true><<<sb, 256, 0, stream>>>(rowptr, scol, sval, bufA, out);
}

// Round 3
// 397.568 us; speedup vs baseline: 9.8553x; 1.4721x over previous
//
#include <hip/hip_runtime.h>
#include <math.h>

#define N_NODES 50000
#define D 128
#define MIN_NORM 1e-15f
#define EPS 1e-5f

// ---- bf16 helpers (round-to-nearest-even) ---------------------------------
__device__ __forceinline__ unsigned f2bf(float f) {
    unsigned u = __float_as_uint(f);
    return (u + 0x7fffu + ((u >> 16) & 1u)) >> 16;
}
__device__ __forceinline__ float bflo(unsigned g) { return __uint_as_float(g << 16); }
__device__ __forceinline__ float bfhi(unsigned g) { return __uint_as_float(g & 0xffff0000u); }

// ---------------------------------------------------------------------------
// h = logmap0(x) -> bf16. One wave per row; lane owns cols {2l, 2l+1}.
// ---------------------------------------------------------------------------
__global__ void logmap0_kernel(const float* __restrict__ x, unsigned* __restrict__ h) {
    int row = blockIdx.x;
    int lane = threadIdx.x;
    const float2* xr = reinterpret_cast<const float2*>(x + (size_t)row * D);
    float2 v = xr[lane];
    float x0 = __shfl(v.x, 0, 64);
    float sq = v.y * v.y + (lane == 0 ? 0.0f : v.x * v.x);
    #pragma unroll
    for (int off = 1; off < 64; off <<= 1) sq += __shfl_xor(sq, off, 64);
    float ynorm = fmaxf(sqrtf(sq), MIN_NORM);
    float theta = fmaxf(x0, 1.0f + EPS);
    float scale = acoshf(theta) / ynorm;
    float ox = (lane == 0) ? 0.0f : v.x * scale;
    float oy = v.y * scale;
    h[(size_t)row * (D / 2) + lane] = f2bf(ox) | (f2bf(oy) << 16);
}

// ---------------------------------------------------------------------------
// CSR build: histogram -> hierarchical scan (3 small kernels) -> scatter
// ---------------------------------------------------------------------------
__global__ void hist_kernel(const int* __restrict__ rows, int* __restrict__ cnt, int E) {
    int e = blockIdx.x * blockDim.x + threadIdx.x;
    if (e < E) atomicAdd(&cnt[rows[e]], 1);
}

// block-local inclusive scan; rowptr[i+1] = local incl; bsum[b] = block total
__global__ __launch_bounds__(256) void scanA_kernel(const int* __restrict__ cnt,
                                                    int* __restrict__ rowptr,
                                                    int* __restrict__ bsum) {
    __shared__ int wsum[4];
    int i = blockIdx.x * 256 + threadIdx.x;
    int lane = threadIdx.x & 63, wid = threadIdx.x >> 6;
    int v = (i < N_NODES) ? cnt[i] : 0;
    int x = v;
    #pragma unroll
    for (int off = 1; off < 64; off <<= 1) {
        int t = __shfl_up(x, off, 64);
        if (lane >= off) x += t;
    }
    if (lane == 63) wsum[wid] = x;
    __syncthreads();
    if (threadIdx.x == 0) {
        int s0 = wsum[0], s1 = wsum[1], s2 = wsum[2];
        wsum[0] = 0; wsum[1] = s0; wsum[2] = s0 + s1; wsum[3] = s0 + s1 + s2;
    }
    __syncthreads();
    int incl = x + wsum[wid];
    if (i < N_NODES) rowptr[i + 1] = incl;
    if (threadIdx.x == 255) bsum[blockIdx.x] = incl;
}

// exclusive scan of block sums (nb <= 256), in place
__global__ __launch_bounds__(256) void scanB_kernel(int* __restrict__ bsum, int nb) {
    __shared__ int wsum[4];
    int lane = threadIdx.x & 63, wid = threadIdx.x >> 6;
    int v = (threadIdx.x < nb) ? bsum[threadIdx.x] : 0;
    int x = v;
    #pragma unroll
    for (int off = 1; off < 64; off <<= 1) {
        int t = __shfl_up(x, off, 64);
        if (lane >= off) x += t;
    }
    if (lane == 63) wsum[wid] = x;
    __syncthreads();
    if (threadIdx.x == 0) {
        int s0 = wsum[0], s1 = wsum[1], s2 = wsum[2];
        wsum[0] = 0; wsum[1] = s0; wsum[2] = s0 + s1; wsum[3] = s0 + s1 + s2;
    }
    __syncthreads();
    int incl = x + wsum[wid];
    if (threadIdx.x < nb) bsum[threadIdx.x] = incl - v;
}

// finalize: rowptr[i+1] += bsum[b]; cursor[i] = exclusive prefix
__global__ __launch_bounds__(256) void scanC_kernel(int* __restrict__ cursor,
                                                    int* __restrict__ rowptr,
                                                    const int* __restrict__ bsum) {
    int i = blockIdx.x * 256 + threadIdx.x;
    if (i >= N_NODES) return;
    int off = bsum[blockIdx.x];
    int incl = rowptr[i + 1] + off;
    int v = cursor[i];
    rowptr[i + 1] = incl;
    cursor[i] = incl - v;
    if (i == 0) rowptr[0] = 0;
}

// single packed 8B scattered write per edge
__global__ void scatter_kernel(const int* __restrict__ rows, const int* __restrict__ cols,
                               const float* __restrict__ vals, int* __restrict__ cursor,
                               int2* __restrict__ epay, int E) {
    int e = blockIdx.x * blockDim.x + threadIdx.x;
    if (e >= E) return;
    int pos = atomicAdd(&cursor[rows[e]], 1);
    epay[pos] = make_int2(cols[e], __float_as_int(vals[e]));
}

// ---------------------------------------------------------------------------
// CSR SpMM over bf16 features: one wave per row, fp32 register accumulate.
// MID: write bf16.  FINAL: fused out = proj(expmap0(acc)) in fp32.
// ---------------------------------------------------------------------------
template <bool FINAL>
__global__ __launch_bounds__(256) void spmm_kernel(const int* __restrict__ rowptr,
                                                   const int2* __restrict__ epay,
                                                   const unsigned* __restrict__ hin,
                                                   void* __restrict__ hout) {
    int wid = threadIdx.x >> 6, lane = threadIdx.x & 63;
    int row = blockIdx.x * 4 + wid;
    if (row >= N_NODES) return;
    int j = rowptr[row], end = rowptr[row + 1];
    float ax = 0.f, ay = 0.f;
#define GATHER(P) { unsigned g = hin[(size_t)(P).x * (D / 2) + lane];          \
                    float vv = __int_as_float((P).y);                          \
                    ax = fmaf(vv, bflo(g), ax); ay = fmaf(vv, bfhi(g), ay); }
    for (; j + 4 <= end; j += 4) {
        int2 p0 = epay[j], p1 = epay[j + 1], p2 = epay[j + 2], p3 = epay[j + 3];
        GATHER(p0); GATHER(p1); GATHER(p2); GATHER(p3);
    }
    for (; j < end; ++j) { int2 p = epay[j]; GATHER(p); }
#undef GATHER
    if (!FINAL) {
        ((unsigned*)hout)[(size_t)row * (D / 2) + lane] = f2bf(ax) | (f2bf(ay) << 16);
    } else {
        // acc col 0 (lane 0, ax) is 0 by construction
        float sq = ay * ay + (lane == 0 ? 0.0f : ax * ax);
        #pragma unroll
        for (int off = 1; off < 64; off <<= 1) sq += __shfl_xor(sq, off, 64);
        float vn = fmaxf(sqrtf(sq), MIN_NORM);
        float sh = sinhf(vn);
        float scale = sh / vn;
        float first = sqrtf(fmaxf(1.0f + sh * sh, EPS));
        float2 o;
        o.x = (lane == 0) ? first : ax * scale;
        o.y = ay * scale;
        reinterpret_cast<float2*>((float*)hout + (size_t)row * D)[lane] = o;
    }
}

// ---------------------------------------------------------------------------
extern "C" void kernel_launch(void* const* d_in, const int* in_sizes, int n_in,
                              void* d_out, int out_size, void* d_ws, size_t ws_size,
                              hipStream_t stream) {
    const float* x    = (const float*)d_in[0];
    const int*   rows = (const int*)d_in[1];
    const int*   cols = (const int*)d_in[2];
    const float* vals = (const float*)d_in[3];
    float* out = (float*)d_out;
    int E = in_sizes[1];

    // workspace layout (≈38.8 MB)
    unsigned* hA    = (unsigned*)d_ws;                       // N*D/2 uints (12.8 MB)
    unsigned* hB    = hA + (size_t)N_NODES * (D / 2);        // 12.8 MB
    int2*     epay  = (int2*)(hB + (size_t)N_NODES * (D / 2)); // E int2 (12.8 MB)
    int*      rowptr = (int*)(epay + E);                     // N+1
    int*      cursor = rowptr + N_NODES + 1;                 // N
    int*      bsum   = cursor + N_NODES;                     // ~196

    int eb = (E + 255) / 256;
    int nb = (N_NODES + 255) / 256;
    int sb = (N_NODES + 3) / 4;

    // h0 = logmap0(x) -> hA (bf16)
    logmap0_kernel<<<N_NODES, 64, 0, stream>>>(x, hA);

    // CSR build
    hipMemsetAsync(cursor, 0, N_NODES * sizeof(int), stream);
    hist_kernel<<<eb, 256, 0, stream>>>(rows, cursor, E);
    scanA_kernel<<<nb, 256, 0, stream>>>(cursor, rowptr, bsum);
    scanB_kernel<<<1, 256, 0, stream>>>(bsum, nb);
    scanC_kernel<<<nb, 256, 0, stream>>>(cursor, rowptr, bsum);
    scatter_kernel<<<eb, 256, 0, stream>>>(rows, cols, vals, cursor, epay, E);

    // layer 1: hA -> hB ; layer 2: hB -> hA ; layer 3 fused: hA -> out (fp32)
    spmm_kernel<false><<<sb, 256, 0, stream>>>(rowptr, epay, hA, hB);
    spmm_kernel<false><<<sb, 256, 0, stream>>>(rowptr, epay, hB, hA);
    spmm_kernel<true ><<<sb, 256, 0, stream>>>(rowptr, epay, hA, out);
}

// Round 4
// 270.265 us; speedup vs baseline: 14.4974x; 1.4710x over previous
//
#include <hip/hip_runtime.h>
#include <math.h>

#define N_NODES 50000
#define D 128
#define MIN_NORM 1e-15f
#define EPS 1e-5f
#define NBUCK 196        // ceil(N_NODES / 256)
#define CHUNK 4096       // edges per block in binning passes

// ---- bf16 helpers (round-to-nearest-even) ---------------------------------
__device__ __forceinline__ unsigned f2bf(float f) {
    unsigned u = __float_as_uint(f);
    return (u + 0x7fffu + ((u >> 16) & 1u)) >> 16;
}
__device__ __forceinline__ float bflo(unsigned g) { return __uint_as_float(g << 16); }
__device__ __forceinline__ float bfhi(unsigned g) { return __uint_as_float(g & 0xffff0000u); }

// ---------------------------------------------------------------------------
// h = logmap0(x) -> bf16. One wave per row; lane owns cols {2l, 2l+1}.
// ---------------------------------------------------------------------------
__global__ void logmap0_kernel(const float* __restrict__ x, unsigned* __restrict__ h) {
    int row = blockIdx.x;
    int lane = threadIdx.x;
    const float2* xr = reinterpret_cast<const float2*>(x + (size_t)row * D);
    float2 v = xr[lane];
    float x0 = __shfl(v.x, 0, 64);
    float sq = v.y * v.y + (lane == 0 ? 0.0f : v.x * v.x);
    #pragma unroll
    for (int off = 1; off < 64; off <<= 1) sq += __shfl_xor(sq, off, 64);
    float ynorm = fmaxf(sqrtf(sq), MIN_NORM);
    float theta = fmaxf(x0, 1.0f + EPS);
    float scale = acoshf(theta) / ynorm;
    float ox = (lane == 0) ? 0.0f : v.x * scale;
    float oy = v.y * scale;
    h[(size_t)row * (D / 2) + lane] = f2bf(ox) | (f2bf(oy) << 16);
}

// ---------------------------------------------------------------------------
// Pass A1: per-bucket edge counts (LDS histogram, one global atomic per
// block*bucket).
// ---------------------------------------------------------------------------
__global__ __launch_bounds__(256) void bcount_kernel(const int* __restrict__ rows,
                                                     int* __restrict__ bcnt, int E) {
    __shared__ int lh[NBUCK];
    for (int i = threadIdx.x; i < NBUCK; i += 256) lh[i] = 0;
    __syncthreads();
    int start = blockIdx.x * CHUNK;
    int end = min(start + CHUNK, E);
    for (int i = start + threadIdx.x; i < end; i += 256)
        atomicAdd(&lh[rows[i] >> 8], 1);
    __syncthreads();
    for (int i = threadIdx.x; i < NBUCK; i += 256)
        if (lh[i]) atomicAdd(&bcnt[i], lh[i]);
}

// exclusive scan of NBUCK bucket counts (1 block); also rowptr[N]=E
__global__ __launch_bounds__(256) void bscan_kernel(const int* __restrict__ bcnt,
                                                    int* __restrict__ bbase,
                                                    int* __restrict__ rowptr, int E) {
    __shared__ int wsum[4];
    int lane = threadIdx.x & 63, wid = threadIdx.x >> 6;
    int v = (threadIdx.x < NBUCK) ? bcnt[threadIdx.x] : 0;
    int x = v;
    #pragma unroll
    for (int off = 1; off < 64; off <<= 1) {
        int t = __shfl_up(x, off, 64);
        if (lane >= off) x += t;
    }
    if (lane == 63) wsum[wid] = x;
    __syncthreads();
    if (threadIdx.x == 0) {
        int s0 = wsum[0], s1 = wsum[1], s2 = wsum[2];
        wsum[0] = 0; wsum[1] = s0; wsum[2] = s0 + s1; wsum[3] = s0 + s1 + s2;
    }
    __syncthreads();
    int incl = x + wsum[wid];
    if (threadIdx.x < NBUCK) bbase[threadIdx.x] = incl - v;
    if (threadIdx.x == NBUCK - 1) bbase[NBUCK] = incl;   // == E
    if (threadIdx.x == 0) rowptr[N_NODES] = E;
}

// ---------------------------------------------------------------------------
// Pass A2: bin edges into bucket regions of tmp. Payload packs
// (rowlocal<<16)|col in .x (col < 50000 < 2^16), val bits in .y.
// ---------------------------------------------------------------------------
__global__ __launch_bounds__(256) void binA_kernel(const int* __restrict__ rows,
                                                   const int* __restrict__ cols,
                                                   const float* __restrict__ vals,
                                                   const int* __restrict__ bbase,
                                                   int* __restrict__ gcur,
                                                   int2* __restrict__ tmp, int E) {
    __shared__ int lh[NBUCK];
    __shared__ int lb[NBUCK];
    for (int i = threadIdx.x; i < NBUCK; i += 256) lh[i] = 0;
    __syncthreads();
    int start = blockIdx.x * CHUNK;
    int end = min(start + CHUNK, E);
    for (int i = start + threadIdx.x; i < end; i += 256)
        atomicAdd(&lh[rows[i] >> 8], 1);
    __syncthreads();
    for (int i = threadIdx.x; i < NBUCK; i += 256) {
        int c = lh[i];
        lb[i] = bbase[i] + (c ? atomicAdd(&gcur[i], c) : 0);
        lh[i] = 0;
    }
    __syncthreads();
    for (int i = start + threadIdx.x; i < end; i += 256) {
        int r = rows[i];
        int b = r >> 8;
        int ofs = atomicAdd(&lh[b], 1);
        tmp[lb[b] + ofs] = make_int2(((r & 255) << 16) | cols[i], __float_as_int(vals[i]));
    }
}

// ---------------------------------------------------------------------------
// Pass B: one block per bucket. Sort bucket edges by local row via a
// 256-entry LDS histogram + scan; emit rowptr and row-sorted epay.
// All scattered writes stay inside this block's ~64KB output region.
// ---------------------------------------------------------------------------
__global__ __launch_bounds__(256) void binB_kernel(const int2* __restrict__ tmp,
                                                   const int* __restrict__ bbase,
                                                   int* __restrict__ rowptr,
                                                   int2* __restrict__ epay) {
    __shared__ int hist[256];
    __shared__ int wsum[4];
    int b = blockIdx.x;
    int base = bbase[b];
    int nloc = bbase[b + 1] - base;
    hist[threadIdx.x] = 0;
    __syncthreads();
    for (int i = threadIdx.x; i < nloc; i += 256)
        atomicAdd(&hist[tmp[base + i].x >> 16], 1);
    __syncthreads();
    int lane = threadIdx.x & 63, wid = threadIdx.x >> 6;
    int v = hist[threadIdx.x];
    int x = v;
    #pragma unroll
    for (int off = 1; off < 64; off <<= 1) {
        int t = __shfl_up(x, off, 64);
        if (lane >= off) x += t;
    }
    if (lane == 63) wsum[wid] = x;
    __syncthreads();
    if (threadIdx.x == 0) {
        int s0 = wsum[0], s1 = wsum[1], s2 = wsum[2];
        wsum[0] = 0; wsum[1] = s0; wsum[2] = s0 + s1; wsum[3] = s0 + s1 + s2;
    }
    __syncthreads();
    int excl = x - v + wsum[wid];
    int g = (b << 8) + threadIdx.x;
    if (g < N_NODES) rowptr[g] = base + excl;
    __syncthreads();
    hist[threadIdx.x] = excl;          // becomes the per-row scatter cursor
    __syncthreads();
    for (int i = threadIdx.x; i < nloc; i += 256) {
        int2 p = tmp[base + i];
        int rl = p.x >> 16;
        int pos = base + atomicAdd(&hist[rl], 1);
        epay[pos] = make_int2(p.x & 0xffff, p.y);
    }
}

// ---------------------------------------------------------------------------
// CSR SpMM over bf16 features: one wave per row, fp32 register accumulate.
// MID: write bf16.  FINAL: fused out = proj(expmap0(acc)) in fp32.
// ---------------------------------------------------------------------------
template <bool FINAL>
__global__ __launch_bounds__(256) void spmm_kernel(const int* __restrict__ rowptr,
                                                   const int2* __restrict__ epay,
                                                   const unsigned* __restrict__ hin,
                                                   void* __restrict__ hout) {
    int wid = threadIdx.x >> 6, lane = threadIdx.x & 63;
    int row = blockIdx.x * 4 + wid;
    if (row >= N_NODES) return;
    int j = rowptr[row], end = rowptr[row + 1];
    float ax = 0.f, ay = 0.f;
#define GATHER(P) { unsigned g = hin[(size_t)(P).x * (D / 2) + lane];          \
                    float vv = __int_as_float((P).y);                          \
                    ax = fmaf(vv, bflo(g), ax); ay = fmaf(vv, bfhi(g), ay); }
    for (; j + 8 <= end; j += 8) {
        int2 p0 = epay[j],     p1 = epay[j + 1], p2 = epay[j + 2], p3 = epay[j + 3];
        int2 p4 = epay[j + 4], p5 = epay[j + 5], p6 = epay[j + 6], p7 = epay[j + 7];
        GATHER(p0); GATHER(p1); GATHER(p2); GATHER(p3);
        GATHER(p4); GATHER(p5); GATHER(p6); GATHER(p7);
    }
    for (; j < end; ++j) { int2 p = epay[j]; GATHER(p); }
#undef GATHER
    if (!FINAL) {
        ((unsigned*)hout)[(size_t)row * (D / 2) + lane] = f2bf(ax) | (f2bf(ay) << 16);
    } else {
        float sq = ay * ay + (lane == 0 ? 0.0f : ax * ax);
        #pragma unroll
        for (int off = 1; off < 64; off <<= 1) sq += __shfl_xor(sq, off, 64);
        float vn = fmaxf(sqrtf(sq), MIN_NORM);
        float sh = sinhf(vn);
        float scale = sh / vn;
        float first = sqrtf(fmaxf(1.0f + sh * sh, EPS));
        float2 o;
        o.x = (lane == 0) ? first : ax * scale;
        o.y = ay * scale;
        reinterpret_cast<float2*>((float*)hout + (size_t)row * D)[lane] = o;
    }
}

// ---------------------------------------------------------------------------
extern "C" void kernel_launch(void* const* d_in, const int* in_sizes, int n_in,
                              void* d_out, int out_size, void* d_ws, size_t ws_size,
                              hipStream_t stream) {
    const float* x    = (const float*)d_in[0];
    const int*   rows = (const int*)d_in[1];
    const int*   cols = (const int*)d_in[2];
    const float* vals = (const float*)d_in[3];
    float* out = (float*)d_out;
    int E = in_sizes[1];

    // workspace layout (~38.6 MB)
    unsigned* hA     = (unsigned*)d_ws;                          // N*D/2 uints (12.8 MB)
    unsigned* hB     = hA + (size_t)N_NODES * (D / 2);           // 12.8 MB
    int2*     tmp    = (int2*)hB;                                // staging aliases hB (E*8B = 12.8 MB)
    int2*     epay   = (int2*)(hB + (size_t)N_NODES * (D / 2));  // E int2 (12.8 MB)
    int*      rowptr = (int*)(epay + E);                         // N+1
    int*      bcnt   = rowptr + N_NODES + 1;                     // NBUCK
    int*      gcur   = bcnt + NBUCK;                             // NBUCK
    int*      bbase  = gcur + NBUCK;                             // NBUCK+1

    int eb = (E + CHUNK - 1) / CHUNK;
    int sb = (N_NODES + 3) / 4;

    // h0 = logmap0(x) -> hA (bf16)
    logmap0_kernel<<<N_NODES, 64, 0, stream>>>(x, hA);

    // CSR build via two-level counting sort (tmp aliases hB: done before SpMM)
    hipMemsetAsync(bcnt, 0, 2 * NBUCK * sizeof(int), stream);    // bcnt + gcur
    bcount_kernel<<<eb, 256, 0, stream>>>(rows, bcnt, E);
    bscan_kernel<<<1, 256, 0, stream>>>(bcnt, bbase, rowptr, E);
    binA_kernel<<<eb, 256, 0, stream>>>(rows, cols, vals, bbase, gcur, tmp, E);
    binB_kernel<<<NBUCK, 256, 0, stream>>>(tmp, bbase, rowptr, epay);

    // layer 1: hA -> hB ; layer 2: hB -> hA ; layer 3 fused: hA -> out (fp32)
    spmm_kernel<false><<<sb, 256, 0, stream>>>(rowptr, epay, hA, hB);
    spmm_kernel<false><<<sb, 256, 0, stream>>>(rowptr, epay, hB, hA);
    spmm_kernel<true ><<<sb, 256, 0, stream>>>(rowptr, epay, hA, out);
}